// Round 18
// baseline (229.187 us; speedup 1.0000x reference)
//
#include <hip/hip_runtime.h>

#define NJ  21
#define FT  6
#define TRS 43   // output tile row stride; odd -> bank-conflict-free
#define TRW 64   // tile rows

// SGPR weight delivery (r2-r5 codegen) + r13 tile flush + FULL occupancy.
// Delivery map (dur / VALU-busy): all-LDS 204/61us, all-readlane 187/108us,
// hybrids 198-202 (monotonic in ds_read count -> no profitable mix).
// s_load->SGPR->fma adds ZERO VALU instr per weight-use: r4/r5 measured only
// 52-59us VALU busy -- cheapest compute stream of any round -- but ran at
// 25% duty because 44KB LDS capped occupancy at 31% and the serial
// s_load->lgkmcnt->fma chains were exposed. Fix: LDS = 11KB tile only ->
// 8 blocks/CU; __launch_bounds__(256,8) -> 8 waves/SIMD hides SMEM latency.

// relu(dot10(W,x)+b) with W,b read at constant indices (scalarizes to s_load)
#define F10(W, Bv, a0,a1,a2,a3,a4,a5,a6,a7,a8,a9) \
  fmaxf(fmaf((W)[9],(a9),fmaf((W)[8],(a8),fmaf((W)[7],(a7),fmaf((W)[6],(a6), \
        fmaf((W)[5],(a5),fmaf((W)[4],(a4),fmaf((W)[3],(a3),fmaf((W)[2],(a2), \
        fmaf((W)[1],(a1),fmaf((W)[0],(a0),(Bv))))))))))), 0.0f)

#define HROW(N,P,j,r) const float h##N##_##r = \
  F10(W1 + (((j)-1)*10 + (r))*10, b1[((j)-1)*10 + (r)], \
      q##N.x, q##N.y, q##N.z, q##N.w, \
      f##P##_0, f##P##_1, f##P##_2, f##P##_3, f##P##_4, f##P##_5);

#define FROW(N,j,r) const float f##N##_##r = \
  F10(W2 + ((j)*6 + (r))*10, b2[(j)*6 + (r)], \
      h##N##_0, h##N##_1, h##N##_2, h##N##_3, h##N##_4, \
      h##N##_5, h##N##_6, h##N##_7, h##N##_8, h##N##_9);

#define DO_JOINT(j,P,N) \
  const float4 q##N = qv[j]; \
  HROW(N,P,j,0) HROW(N,P,j,1) HROW(N,P,j,2) HROW(N,P,j,3) HROW(N,P,j,4) \
  HROW(N,P,j,5) HROW(N,P,j,6) HROW(N,P,j,7) HROW(N,P,j,8) HROW(N,P,j,9) \
  FROW(N,j,0) FROW(N,j,1) FROW(N,j,2) FROW(N,j,3) FROW(N,j,4) FROW(N,j,5)

#define PUT6(p, X) { (p)[0]=f##X##_0; (p)[1]=f##X##_1; (p)[2]=f##X##_2; \
                     (p)[3]=f##X##_3; (p)[4]=f##X##_4; (p)[5]=f##X##_5; }

// Quarter flush: wave q PUTs its 64 rows, then ALL threads stream them out.
#define QFLUSH(k, q, N0,N1,N2,N3,N4,N5,N6) \
  __syncthreads(); \
  if ((tid >> 6) == (q)) { \
    float* tr_ = tile + (tid & 63) * TRS; \
    PUT6(tr_+0,  N0) PUT6(tr_+6,  N1) PUT6(tr_+12, N2) PUT6(tr_+18, N3) \
    PUT6(tr_+24, N4) PUT6(tr_+30, N5) PUT6(tr_+36, N6) \
  } \
  __syncthreads(); \
  for (int i_ = tid; i_ < TRW*42; i_ += 256) { \
    const int row_ = i_ / 42, col_ = i_ - row_ * 42; \
    out[(size_t)(base + (q)*TRW + row_) * 126 + (k)*42 + col_] = \
        tile[row_ * TRS + col_]; \
  }

#define CHUNK_FLUSH(k, N0,N1,N2,N3,N4,N5,N6) \
  QFLUSH(k, 0, N0,N1,N2,N3,N4,N5,N6) \
  QFLUSH(k, 1, N0,N1,N2,N3,N4,N5,N6) \
  QFLUSH(k, 2, N0,N1,N2,N3,N4,N5,N6) \
  QFLUSH(k, 3, N0,N1,N2,N3,N4,N5,N6)

__global__ __launch_bounds__(256, 8) void se_kernel(
    const float* __restrict__ quat,   // [B, 21, 4]
    const float* __restrict__ W1r,    // [10, 4]
    const float* __restrict__ b1r,    // [10]
    const float* __restrict__ W1,     // [20, 10, 10]
    const float* __restrict__ b1,     // [20, 10]
    const float* __restrict__ W2,     // [21, 6, 10]
    const float* __restrict__ b2,     // [21, 6]
    float*       __restrict__ out,    // [B, 126]
    int B)
{
    __shared__ float tile[TRW * TRS];  // 11008 B only -> 8 blocks/CU

    const int tid  = threadIdx.x;
    const int base = blockIdx.x * 256;

    const int bcl = min(base + tid, B - 1);
    const float4* __restrict__ qv =
        reinterpret_cast<const float4*>(quat) + (size_t)bcl * NJ;

    // ---- chunk 0: joints 0..6 ----
    const float4 q0 = qv[0];
#define H0ROW(r) const float h0_##r = fmaxf( \
    fmaf(W1r[(r)*4+3], q0.w, fmaf(W1r[(r)*4+2], q0.z, \
    fmaf(W1r[(r)*4+1], q0.y, fmaf(W1r[(r)*4+0], q0.x, b1r[r])))), 0.0f);
    H0ROW(0) H0ROW(1) H0ROW(2) H0ROW(3) H0ROW(4)
    H0ROW(5) H0ROW(6) H0ROW(7) H0ROW(8) H0ROW(9)
#undef H0ROW
    FROW(0,0,0) FROW(0,0,1) FROW(0,0,2) FROW(0,0,3) FROW(0,0,4) FROW(0,0,5)

    DO_JOINT(1,0,1)  DO_JOINT(2,0,2)  DO_JOINT(3,0,3)
    DO_JOINT(4,1,4)  DO_JOINT(5,2,5)  DO_JOINT(6,3,6)
    CHUNK_FLUSH(0, 0,1,2,3,4,5,6)

    // ---- chunk 1: joints 7..13 ----
    DO_JOINT(7,4,7)   DO_JOINT(8,5,8)   DO_JOINT(9,6,9)
    DO_JOINT(10,7,10) DO_JOINT(11,8,11)
    DO_JOINT(12,9,12) DO_JOINT(13,9,13)
    CHUNK_FLUSH(1, 7,8,9,10,11,12,13)

    // ---- chunk 2: joints 14..20 ----
    DO_JOINT(14,9,14)  DO_JOINT(15,12,15) DO_JOINT(16,13,16)
    DO_JOINT(17,14,17) DO_JOINT(18,16,18)
    DO_JOINT(19,17,19) DO_JOINT(20,18,20)
    CHUNK_FLUSH(2, 14,15,16,17,18,19,20)
}

extern "C" void kernel_launch(void* const* d_in, const int* in_sizes, int n_in,
                              void* d_out, int out_size, void* d_ws, size_t ws_size,
                              hipStream_t stream) {
    const float* quat = (const float*)d_in[0];
    const float* W1r  = (const float*)d_in[1];
    const float* b1r  = (const float*)d_in[2];
    const float* W1   = (const float*)d_in[3];
    const float* b1   = (const float*)d_in[4];
    const float* W2   = (const float*)d_in[5];
    const float* b2   = (const float*)d_in[6];
    float* out = (float*)d_out;

    const int B = in_sizes[0] / (NJ * 4);
    const int blocks = (B + 255) / 256;
    se_kernel<<<blocks, 256, 0, stream>>>(quat, W1r, b1r, W1, b1, W2, b2, out, B);
}

// Round 19
// 199.590 us; speedup vs baseline: 1.1483x; 1.1483x over previous
//
#include <hip/hip_runtime.h>

#define NJ  21
#define FT  6
#define JW  176   // packed per-joint weights: 110 (L1) + 66 (L2)
#define TC2 23    // tile row stride in float2 (46 floats: gcd(46,64)=2 -> 2-way, free)

// Barrier-free structure. r12 (champion, 187us): readlane delivery but 25
// __syncthreads (each = full waitcnt drain + scheduling wall) + 3.3K-load
// LDS staging prologue. Delivery map closed: LDS 204 / RL 187 / hybrid
// 198-202 / SMEM 229 -> RL wins; remaining cost is structure.
// r19: 64-thread (1-wave) blocks, weights read from a PRE-PACKED global
// buffer (d_ws, tiny prep kernel) -> no staging, no barriers anywhere.
// Per-wave-private LDS tile (DS ops are in-order within a wave -> PUT/
// streamout/reuse need no sync). Global stores drain on vmcnt slack ->
// streamout overlaps next chunk's compute; compiler schedules freely.

__device__ __forceinline__ float RL(float v, int l) {
    return __int_as_float(__builtin_amdgcn_readlane(__float_as_int(v), l));
}
// weight k (0..175) of joint-block N, lane-resident in 3 VGPRs
#define RW(N,k) ((k) < 64 ? RL(wv##N##_0, (k)) : \
                 (k) < 128 ? RL(wv##N##_1, (k)-64) : RL(wv##N##_2, (k)-128))

// hidden row r (weights k = r*11 + 0..9, bias at r*11+10)
#define HROW(N,P,r) const float h##N##_##r = fmaxf( \
  fmaf(RW(N,(r)*11+9), f##P##_5, fmaf(RW(N,(r)*11+8), f##P##_4, \
  fmaf(RW(N,(r)*11+7), f##P##_3, fmaf(RW(N,(r)*11+6), f##P##_2, \
  fmaf(RW(N,(r)*11+5), f##P##_1, fmaf(RW(N,(r)*11+4), f##P##_0, \
  fmaf(RW(N,(r)*11+3), q##N.w,   fmaf(RW(N,(r)*11+2), q##N.z, \
  fmaf(RW(N,(r)*11+1), q##N.y,   fmaf(RW(N,(r)*11+0), q##N.x, \
  RW(N,(r)*11+10))))))))))), 0.0f);

// output row r (weights k = 110 + r*11 + 0..9, bias at +10)
#define FROW(N,r) const float f##N##_##r = fmaxf( \
  fmaf(RW(N,110+(r)*11+9), h##N##_9, fmaf(RW(N,110+(r)*11+8), h##N##_8, \
  fmaf(RW(N,110+(r)*11+7), h##N##_7, fmaf(RW(N,110+(r)*11+6), h##N##_6, \
  fmaf(RW(N,110+(r)*11+5), h##N##_5, fmaf(RW(N,110+(r)*11+4), h##N##_4, \
  fmaf(RW(N,110+(r)*11+3), h##N##_3, fmaf(RW(N,110+(r)*11+2), h##N##_2, \
  fmaf(RW(N,110+(r)*11+1), h##N##_1, fmaf(RW(N,110+(r)*11+0), h##N##_0, \
  RW(N,110+(r)*11+10))))))))))), 0.0f);

// per-joint PUT into this lane's private tile row (f dies here unless a child needs it)
#define PUTF(N,jj) { \
  tile2[lane*TC2 + (jj)*3 + 0] = make_float2(f##N##_0, f##N##_1); \
  tile2[lane*TC2 + (jj)*3 + 1] = make_float2(f##N##_2, f##N##_3); \
  tile2[lane*TC2 + (jj)*3 + 2] = make_float2(f##N##_4, f##N##_5); }

#define DO_JOINT(j,P,N,jj) \
  const float4 q##N = qv[j]; \
  const float wv##N##_0 = jwg[(j)*JW + lane]; \
  const float wv##N##_1 = jwg[(j)*JW + 64 + lane]; \
  const float wv##N##_2 = jwg[(j)*JW + 128 + lane]; \
  HROW(N,P,0) HROW(N,P,1) HROW(N,P,2) HROW(N,P,3) HROW(N,P,4) \
  HROW(N,P,5) HROW(N,P,6) HROW(N,P,7) HROW(N,P,8) HROW(N,P,9) \
  FROW(N,0) FROW(N,1) FROW(N,2) FROW(N,3) FROW(N,4) FROW(N,5) \
  PUTF(N,jj)

// stream the wave's 64x21 float2 chunk out, fully coalesced; no sync needed
#define STREAMOUT(k) { \
  _Pragma("unroll") \
  for (int i_ = 0; i_ < 21; ++i_) { \
    const int flat_ = i_*64 + lane; \
    const int row_ = flat_ / 21, col_ = flat_ - row_*21; \
    if (base + row_ < B) \
      out2[(size_t)(base + row_)*63 + (k)*21 + col_] = tile2[row_*TC2 + col_]; \
  } }

// ---- prep: pack weights into d_ws in the jw layout (runs every call) ----
__global__ __launch_bounds__(256) void pack_kernel(
    const float* __restrict__ W1r, const float* __restrict__ b1r,
    const float* __restrict__ W1,  const float* __restrict__ b1,
    const float* __restrict__ W2,  const float* __restrict__ b2,
    float* __restrict__ jw)
{
    const int tid = threadIdx.x;
    for (int i = tid; i < 20*110; i += 256) {          // joints 1..20, layer 1
        const int j = i / 110, k = i % 110, r = k / 11, c = k % 11;
        jw[(j+1)*JW + k] = (c < 10) ? W1[j*100 + r*10 + c] : b1[j*10 + r];
    }
    for (int i = tid; i < 20*66; i += 256) {           // joints 1..20, layer 2
        const int j = i / 66, k = i % 66, r = k / 11, c = k % 11;
        jw[(j+1)*JW + 110 + k] = (c < 10) ? W2[(j+1)*60 + r*10 + c]
                                          : b2[(j+1)*6 + r];
    }
    if (tid < 50) {                                    // root layer 1: 5/row
        const int r = tid / 5, c = tid % 5;
        jw[tid] = (c < 4) ? W1r[r*4 + c] : b1r[r];
    }
    if (tid < 66) {                                    // root layer 2 at +50
        const int r = tid / 11, c = tid % 11;
        jw[50 + tid] = (c < 10) ? W2[r*10 + c] : b2[r];
    }
}

__global__ __launch_bounds__(64) void se_kernel(
    const float* __restrict__ quat,   // [B, 21, 4]
    const float* __restrict__ jwg,    // [21*176] packed weights (d_ws)
    float*       __restrict__ out,    // [B, 126]
    int B)
{
    __shared__ float2 tile2[64 * TC2];                 // 11776 B -> 13 blk/CU

    const int lane = threadIdx.x;                      // 0..63
    const int base = blockIdx.x * 64;
    const int e    = min(base + lane, B - 1);

    const float4* __restrict__ qv =
        reinterpret_cast<const float4*>(quat) + (size_t)e * NJ;
    float2* __restrict__ out2 = reinterpret_cast<float2*>(out);

    // ---- chunk 0: joints 0..6 ----
    const float4 q0 = qv[0];
    const float wv0_0 = jwg[lane];
    const float wv0_1 = jwg[64 + lane];
    const float wv0_2 = jwg[128 + lane];   // dead-branch ref in RW; folds away
#define H0ROW(r) const float h0_##r = fmaxf( \
    fmaf(RW(0,(r)*5+3), q0.w, fmaf(RW(0,(r)*5+2), q0.z, \
    fmaf(RW(0,(r)*5+1), q0.y, fmaf(RW(0,(r)*5+0), q0.x, RW(0,(r)*5+4))))), 0.0f);
    H0ROW(0) H0ROW(1) H0ROW(2) H0ROW(3) H0ROW(4)
    H0ROW(5) H0ROW(6) H0ROW(7) H0ROW(8) H0ROW(9)
#undef H0ROW
#define F0ROW(r) const float f0_##r = fmaxf( \
    fmaf(RW(0,50+(r)*11+9), h0_9, fmaf(RW(0,50+(r)*11+8), h0_8, \
    fmaf(RW(0,50+(r)*11+7), h0_7, fmaf(RW(0,50+(r)*11+6), h0_6, \
    fmaf(RW(0,50+(r)*11+5), h0_5, fmaf(RW(0,50+(r)*11+4), h0_4, \
    fmaf(RW(0,50+(r)*11+3), h0_3, fmaf(RW(0,50+(r)*11+2), h0_2, \
    fmaf(RW(0,50+(r)*11+1), h0_1, fmaf(RW(0,50+(r)*11+0), h0_0, \
    RW(0,50+(r)*11+10))))))))))), 0.0f);
    F0ROW(0) F0ROW(1) F0ROW(2) F0ROW(3) F0ROW(4) F0ROW(5)
#undef F0ROW
    PUTF(0,0)

    DO_JOINT(1,0,1,1)   DO_JOINT(2,0,2,2)   DO_JOINT(3,0,3,3)
    DO_JOINT(4,1,4,4)   DO_JOINT(5,2,5,5)   DO_JOINT(6,3,6,6)
    STREAMOUT(0)

    // ---- chunk 1: joints 7..13 (f4,f5,f6 persist in regs across streamout) ----
    DO_JOINT(7,4,7,0)    DO_JOINT(8,5,8,1)    DO_JOINT(9,6,9,2)
    DO_JOINT(10,7,10,3)  DO_JOINT(11,8,11,4)
    DO_JOINT(12,9,12,5)  DO_JOINT(13,9,13,6)
    STREAMOUT(1)

    // ---- chunk 2: joints 14..20 (f9,f12,f13 persist) ----
    DO_JOINT(14,9,14,0)   DO_JOINT(15,12,15,1)  DO_JOINT(16,13,16,2)
    DO_JOINT(17,14,17,3)  DO_JOINT(18,16,18,4)
    DO_JOINT(19,17,19,5)  DO_JOINT(20,18,20,6)
    STREAMOUT(2)
}

extern "C" void kernel_launch(void* const* d_in, const int* in_sizes, int n_in,
                              void* d_out, int out_size, void* d_ws, size_t ws_size,
                              hipStream_t stream) {
    const float* quat = (const float*)d_in[0];
    const float* W1r  = (const float*)d_in[1];
    const float* b1r  = (const float*)d_in[2];
    const float* W1   = (const float*)d_in[3];
    const float* b1   = (const float*)d_in[4];
    const float* W2   = (const float*)d_in[5];
    const float* b2   = (const float*)d_in[6];
    float* out = (float*)d_out;
    float* jw  = (float*)d_ws;                         // 21*176*4 = 14.8 KB

    const int B = in_sizes[0] / (NJ * 4);
    pack_kernel<<<1, 256, 0, stream>>>(W1r, b1r, W1, b1, W2, b2, jw);
    const int blocks = (B + 63) / 64;
    se_kernel<<<blocks, 64, 0, stream>>>(quat, jw, out, B);
}

// Round 20
// 199.546 us; speedup vs baseline: 1.1485x; 1.0002x over previous
//
#include <hip/hip_runtime.h>

#define NJ  21
#define FT  6
#define JW  176   // packed per-joint weights: 110 (L1) + 66 (L2)
#define TST 19    // tile row stride in float2 (max 18 cols + 1; lane stride 38 banks -> 2-way, free)

// Barrier-free (r19) at HIGH occupancy. r19: 53% VALU at 29% occ (1-wave
// blocks, 11.8KB/wave tile) -> per-wave duty 1.8x r12's, starved of waves.
// r20: 4 chunks of <=6 joints -> 9.5KB/wave tile; 256-thread blocks, 4 waves
// each with a PRIVATE tile region, zero barriers (DS ops wave-ordered).
// LDS 38.9KB -> 4 blocks/CU = 16 waves = 50% occ. Weights from pre-packed
// global (r19-proven: L1-resident, no staging). Streamout spans 120-144B
// per row (vs 168B) -> accept ~+15% write amp for 1.7x occupancy.

__device__ __forceinline__ float RL(float v, int l) {
    return __int_as_float(__builtin_amdgcn_readlane(__float_as_int(v), l));
}
#define RW(N,k) ((k) < 64 ? RL(wv##N##_0, (k)) : \
                 (k) < 128 ? RL(wv##N##_1, (k)-64) : RL(wv##N##_2, (k)-128))

// hidden row r (weights k = r*11 + 0..9, bias at r*11+10)
#define HROW(N,P,r) const float h##N##_##r = fmaxf( \
  fmaf(RW(N,(r)*11+9), f##P##_5, fmaf(RW(N,(r)*11+8), f##P##_4, \
  fmaf(RW(N,(r)*11+7), f##P##_3, fmaf(RW(N,(r)*11+6), f##P##_2, \
  fmaf(RW(N,(r)*11+5), f##P##_1, fmaf(RW(N,(r)*11+4), f##P##_0, \
  fmaf(RW(N,(r)*11+3), q##N.w,   fmaf(RW(N,(r)*11+2), q##N.z, \
  fmaf(RW(N,(r)*11+1), q##N.y,   fmaf(RW(N,(r)*11+0), q##N.x, \
  RW(N,(r)*11+10))))))))))), 0.0f);

// output row r (weights k = 110 + r*11 + 0..9, bias at +10)
#define FROW(N,r) const float f##N##_##r = fmaxf( \
  fmaf(RW(N,110+(r)*11+9), h##N##_9, fmaf(RW(N,110+(r)*11+8), h##N##_8, \
  fmaf(RW(N,110+(r)*11+7), h##N##_7, fmaf(RW(N,110+(r)*11+6), h##N##_6, \
  fmaf(RW(N,110+(r)*11+5), h##N##_5, fmaf(RW(N,110+(r)*11+4), h##N##_4, \
  fmaf(RW(N,110+(r)*11+3), h##N##_3, fmaf(RW(N,110+(r)*11+2), h##N##_2, \
  fmaf(RW(N,110+(r)*11+1), h##N##_1, fmaf(RW(N,110+(r)*11+0), h##N##_0, \
  RW(N,110+(r)*11+10))))))))))), 0.0f);

// PUT into this lane's row of the wave-private tile (col jj within chunk)
#define PUTF(N,jj) { \
  tilew[lane*TST + (jj)*3 + 0] = make_float2(f##N##_0, f##N##_1); \
  tilew[lane*TST + (jj)*3 + 1] = make_float2(f##N##_2, f##N##_3); \
  tilew[lane*TST + (jj)*3 + 2] = make_float2(f##N##_4, f##N##_5); }

#define DO_JOINT(j,P,N,jj) \
  const float4 q##N = qv[j]; \
  const float wv##N##_0 = jwg[(j)*JW + lane]; \
  const float wv##N##_1 = jwg[(j)*JW + 64 + lane]; \
  const float wv##N##_2 = jwg[(j)*JW + 128 + lane]; \
  HROW(N,P,0) HROW(N,P,1) HROW(N,P,2) HROW(N,P,3) HROW(N,P,4) \
  HROW(N,P,5) HROW(N,P,6) HROW(N,P,7) HROW(N,P,8) HROW(N,P,9) \
  FROW(N,0) FROW(N,1) FROW(N,2) FROW(N,3) FROW(N,4) FROW(N,5) \
  PUTF(N,jj)

// stream the wave's 64 x C2 float2 chunk out; no sync needed (wave-ordered DS)
#define STREAMOUT(C2, O2) { \
  _Pragma("unroll") \
  for (int i_ = 0; i_ < (C2); ++i_) { \
    const int flat_ = i_*64 + lane; \
    const int row_ = flat_ / (C2), col_ = flat_ - row_*(C2); \
    if (wbase + row_ < B) \
      out2[(size_t)(wbase + row_)*63 + (O2) + col_] = tilew[row_*TST + col_]; \
  } }

// ---- prep: pack weights into d_ws in the jw layout ----
__global__ __launch_bounds__(256) void pack_kernel(
    const float* __restrict__ W1r, const float* __restrict__ b1r,
    const float* __restrict__ W1,  const float* __restrict__ b1,
    const float* __restrict__ W2,  const float* __restrict__ b2,
    float* __restrict__ jw)
{
    const int tid = threadIdx.x;
    for (int i = tid; i < 20*110; i += 256) {          // joints 1..20, layer 1
        const int j = i / 110, k = i % 110, r = k / 11, c = k % 11;
        jw[(j+1)*JW + k] = (c < 10) ? W1[j*100 + r*10 + c] : b1[j*10 + r];
    }
    for (int i = tid; i < 20*66; i += 256) {           // joints 1..20, layer 2
        const int j = i / 66, k = i % 66, r = k / 11, c = k % 11;
        jw[(j+1)*JW + 110 + k] = (c < 10) ? W2[(j+1)*60 + r*10 + c]
                                          : b2[(j+1)*6 + r];
    }
    if (tid < 50) {                                    // root layer 1: 5/row
        const int r = tid / 5, c = tid % 5;
        jw[tid] = (c < 4) ? W1r[r*4 + c] : b1r[r];
    }
    if (tid < 66) {                                    // root layer 2 at +50
        const int r = tid / 11, c = tid % 11;
        jw[50 + tid] = (c < 10) ? W2[r*10 + c] : b2[r];
    }
}

__global__ __launch_bounds__(256) void se_kernel(
    const float* __restrict__ quat,   // [B, 21, 4]
    const float* __restrict__ jwg,    // [21*176] packed weights (d_ws)
    float*       __restrict__ out,    // [B, 126]
    int B)
{
    __shared__ float2 tile2[4 * 64 * TST];             // 38912 B -> 4 blk/CU

    const int tid   = threadIdx.x;
    const int lane  = tid & 63;
    const int w     = tid >> 6;
    const int wbase = blockIdx.x * 256 + w * 64;       // wave's 64 elements
    const int e     = min(wbase + lane, B - 1);

    const float4* __restrict__ qv =
        reinterpret_cast<const float4*>(quat) + (size_t)e * NJ;
    float2* __restrict__ out2  = reinterpret_cast<float2*>(out);
    float2* __restrict__ tilew = tile2 + w * 64 * TST; // wave-private region

    // ---- chunk 0: joints 0..5 (cols 0..17) ----
    const float4 q0 = qv[0];
    const float wv0_0 = jwg[lane];
    const float wv0_1 = jwg[64 + lane];
    const float wv0_2 = jwg[128 + lane];   // dead-branch ref in RW; folds away
#define H0ROW(r) const float h0_##r = fmaxf( \
    fmaf(RW(0,(r)*5+3), q0.w, fmaf(RW(0,(r)*5+2), q0.z, \
    fmaf(RW(0,(r)*5+1), q0.y, fmaf(RW(0,(r)*5+0), q0.x, RW(0,(r)*5+4))))), 0.0f);
    H0ROW(0) H0ROW(1) H0ROW(2) H0ROW(3) H0ROW(4)
    H0ROW(5) H0ROW(6) H0ROW(7) H0ROW(8) H0ROW(9)
#undef H0ROW
#define F0ROW(r) const float f0_##r = fmaxf( \
    fmaf(RW(0,50+(r)*11+9), h0_9, fmaf(RW(0,50+(r)*11+8), h0_8, \
    fmaf(RW(0,50+(r)*11+7), h0_7, fmaf(RW(0,50+(r)*11+6), h0_6, \
    fmaf(RW(0,50+(r)*11+5), h0_5, fmaf(RW(0,50+(r)*11+4), h0_4, \
    fmaf(RW(0,50+(r)*11+3), h0_3, fmaf(RW(0,50+(r)*11+2), h0_2, \
    fmaf(RW(0,50+(r)*11+1), h0_1, fmaf(RW(0,50+(r)*11+0), h0_0, \
    RW(0,50+(r)*11+10))))))))))), 0.0f);
    F0ROW(0) F0ROW(1) F0ROW(2) F0ROW(3) F0ROW(4) F0ROW(5)
#undef F0ROW
    PUTF(0,0)

    DO_JOINT(1,0,1,1)   DO_JOINT(2,0,2,2)   DO_JOINT(3,0,3,3)
    DO_JOINT(4,1,4,4)   DO_JOINT(5,2,5,5)
    STREAMOUT(18, 0)

    // ---- chunk 1: joints 6..10 (cols 18..32); f3,f4,f5 live from chunk 0 ----
    DO_JOINT(6,3,6,0)   DO_JOINT(7,4,7,1)   DO_JOINT(8,5,8,2)
    DO_JOINT(9,6,9,3)   DO_JOINT(10,7,10,4)
    STREAMOUT(15, 18)

    // ---- chunk 2: joints 11..15 (cols 33..47); f8,f9 live ----
    DO_JOINT(11,8,11,0)  DO_JOINT(12,9,12,1)  DO_JOINT(13,9,13,2)
    DO_JOINT(14,9,14,3)  DO_JOINT(15,12,15,4)
    STREAMOUT(15, 33)

    // ---- chunk 3: joints 16..20 (cols 48..62); f13,f14 live ----
    DO_JOINT(16,13,16,0) DO_JOINT(17,14,17,1) DO_JOINT(18,16,18,2)
    DO_JOINT(19,17,19,3) DO_JOINT(20,18,20,4)
    STREAMOUT(15, 48)
}

extern "C" void kernel_launch(void* const* d_in, const int* in_sizes, int n_in,
                              void* d_out, int out_size, void* d_ws, size_t ws_size,
                              hipStream_t stream) {
    const float* quat = (const float*)d_in[0];
    const float* W1r  = (const float*)d_in[1];
    const float* b1r  = (const float*)d_in[2];
    const float* W1   = (const float*)d_in[3];
    const float* b1   = (const float*)d_in[4];
    const float* W2   = (const float*)d_in[5];
    const float* b2   = (const float*)d_in[6];
    float* out = (float*)d_out;
    float* jw  = (float*)d_ws;                         // 21*176*4 = 14.8 KB

    const int B = in_sizes[0] / (NJ * 4);
    pack_kernel<<<1, 256, 0, stream>>>(W1r, b1r, W1, b1, W2, b2, jw);
    const int blocks = (B + 255) / 256;
    se_kernel<<<blocks, 256, 0, stream>>>(quat, jw, out, B);
}